// Round 6
// baseline (389.805 us; speedup 1.0000x reference)
//
#include <hip/hip_runtime.h>

// Problem constants: N=262144, D=32, Q=4, K=256
#define DIMS 32
#define NQ   4
#define KC   256
#define BETA 0.25f
#define FLTMAX 3.402823466e38f

typedef __attribute__((ext_vector_type(8))) short  short8;   // 8 bf16 (4 VGPRs)
typedef __attribute__((ext_vector_type(4))) float  floatx4;  // MFMA acc

// TRANSPOSED MFMA: A = codes (from LDS, negated, trunc-split bf16), B = residuals.
// D[row = code-in-tile = qo*4+i][col = point = l&15]  (C/D: col=lane&15, row=(lane>>4)*4+reg)
// => each point's scores live in lanes {qo*16+cl} — the same lanes that own its dims:
//    2-round shfl reduction, no broadcast block.
// acc init = 0.5||c||^2 + 0.5||r||^2; codes negated at staging => acc = dist^2/2.
// Code index packed in low 8 mantissa bits as (tt<<2)|i (lane-uniform -> v_and_or w/ SGPR),
// resolved to full code (tt*16+qo*4+i) before cross-reg/lane merging.
__launch_bounds__(256, 4)
__global__ void rvq_kernel(const float* __restrict__ x,
                           const float* __restrict__ cb,      // [NQ, KC, DIMS]
                           float* __restrict__ out_xq,        // [N, DIMS]
                           float* __restrict__ out_loss,      // [1] pre-zeroed
                           float* __restrict__ out_idx)       // [N, NQ] as float
{
    // entry e = tt*64 + qo*16 + cl  <->  code tt*16+cl, dim-octet qo; 16 B each.
    __shared__ __align__(16) short s_hi[1024 * 8];   // 16 KB
    __shared__ __align__(16) short s_lo[1024 * 8];   // 16 KB
    __shared__ float s_hn[KC];                       // 1 KB: 0.5*||c||^2
    __shared__ float s_ws[4];

    const int t  = threadIdx.x;
    const int l  = t & 63;
    const int w  = t >> 6;
    const int qo = l >> 4;       // dim-octet (0..3)
    const int cl = l & 15;       // point-in-group / code-in-tile

    const int base = blockIdx.x * 128 + w * 32;   // wave covers 32 points (2 groups of 16)

    // ---- residuals: [group][8 dims], 16 VGPRs ----
    float r[2][8];
    #pragma unroll
    for (int g = 0; g < 2; ++g) {
        const float4* xp = (const float4*)(x + (size_t)(base + g*16 + cl) * DIMS + qo * 8);
        float4 a = xp[0], c = xp[1];
        r[g][0]=a.x; r[g][1]=a.y; r[g][2]=a.z; r[g][3]=a.w;
        r[g][4]=c.x; r[g][5]=c.y; r[g][6]=c.z; r[g][7]=c.w;
    }

    float la = 0.f;   // sum over own dims of ||r_new||^2, all stages

    for (int q = 0; q < NQ; ++q) {
        const float* cbq = cb + (size_t)q * KC * DIMS;
        __syncthreads();   // previous stage's LDS consumers done

        // ---- stage: half-norms (exact fp32), thread t <-> code t ----
        {
            const float4* c4 = (const float4*)(cbq + (size_t)t * DIMS);
            float s0=0.f,s1=0.f,s2=0.f,s3=0.f;
            #pragma unroll
            for (int j = 0; j < 8; ++j) {
                float4 f = c4[j];
                s0 = fmaf(f.x,f.x,s0); s1 = fmaf(f.y,f.y,s1);
                s2 = fmaf(f.z,f.z,s2); s3 = fmaf(f.w,f.w,s3);
            }
            s_hn[t] = 0.5f * ((s0+s1)+(s2+s3));
        }
        // ---- stage: negated trunc-split codebook; 1 thread = 1 full 16B entry ----
        // write pattern: lanes -> sequential dwords => conflict-free ds_write_b128
        #pragma unroll
        for (int it = 0; it < 4; ++it) {
            int e = it * 256 + t;
            const float4* src = (const float4*)(cbq + (size_t)((e>>6)*16 + (e&15)) * DIMS
                                                + ((e>>4)&3) * 8);
            float4 f0 = src[0], f1 = src[1];
            unsigned u[8];
            u[0]=__float_as_uint(f0.x)^0x80000000u; u[1]=__float_as_uint(f0.y)^0x80000000u;
            u[2]=__float_as_uint(f0.z)^0x80000000u; u[3]=__float_as_uint(f0.w)^0x80000000u;
            u[4]=__float_as_uint(f1.x)^0x80000000u; u[5]=__float_as_uint(f1.y)^0x80000000u;
            u[6]=__float_as_uint(f1.z)^0x80000000u; u[7]=__float_as_uint(f1.w)^0x80000000u;
            int4 hp, lp;
            int* hpi = (int*)&hp; int* lpi = (int*)&lp;
            #pragma unroll
            for (int p = 0; p < 4; ++p) {
                unsigned a = u[2*p], b = u[2*p+1];
                hpi[p] = (int)((b & 0xFFFF0000u) | (a >> 16));
                float ea = __uint_as_float(a) - __uint_as_float(a & 0xFFFF0000u);
                float eb = __uint_as_float(b) - __uint_as_float(b & 0xFFFF0000u);
                unsigned ua = __float_as_uint(ea), ub = __float_as_uint(eb);
                lpi[p] = (int)((ub & 0xFFFF0000u) | (ua >> 16));
            }
            *(int4*)(&s_hi[e << 3]) = hp;
            *(int4*)(&s_lo[e << 3]) = lp;
        }
        __syncthreads();

        // ---- B-fragments: trunc-split bf16 of residual (unnegated) ----
        short8 rh[2], rl[2];
        #pragma unroll
        for (int g = 0; g < 2; ++g) {
            int4 hp, lp;
            int* hpi = (int*)&hp; int* lpi = (int*)&lp;
            #pragma unroll
            for (int p = 0; p < 4; ++p) {
                unsigned a = __float_as_uint(r[g][2*p]);
                unsigned b = __float_as_uint(r[g][2*p+1]);
                hpi[p] = (int)((b & 0xFFFF0000u) | (a >> 16));
                float ea = r[g][2*p]   - __uint_as_float(a & 0xFFFF0000u);
                float eb = r[g][2*p+1] - __uint_as_float(b & 0xFFFF0000u);
                unsigned ua = __float_as_uint(ea), ub = __float_as_uint(eb);
                lpi[p] = (int)((ub & 0xFFFF0000u) | (ua >> 16));
            }
            rh[g] = *(short8*)&hp;
            rl[g] = *(short8*)&lp;
        }

        // ---- ||r||^2 per point (every lane ends with its point's value) ----
        float rn[2], hrn[2];
        #pragma unroll
        for (int g = 0; g < 2; ++g) {
            float p0 = 0.f;
            #pragma unroll
            for (int j = 0; j < 8; ++j) p0 = fmaf(r[g][j], r[g][j], p0);
            p0 += __shfl_xor(p0, 16);
            p0 += __shfl_xor(p0, 32);
            rn[g] = p0;
            hrn[g] = 0.5f * p0;
        }

        // ---- MFMA tile loop ----
        float m1[2][4], m2[2][4];
        #pragma unroll
        for (int g = 0; g < 2; ++g)
            #pragma unroll
            for (int i = 0; i < 4; ++i) { m1[g][i] = FLTMAX; m2[g][i] = FLTMAX; }

        #pragma unroll 4
        for (int tt = 0; tt < 16; ++tt) {
            const short8 ch  = *(const short8*)(&s_hi[((tt << 6) + l) << 3]);
            const short8 cl8 = *(const short8*)(&s_lo[((tt << 6) + l) << 3]);
            const float4 hn4 = *(const float4*)(&s_hn[(tt << 4) + (qo << 2)]);  // broadcast
            #pragma unroll
            for (int g = 0; g < 2; ++g) {
                floatx4 acc = {hn4.x + hrn[g], hn4.y + hrn[g],
                               hn4.z + hrn[g], hn4.w + hrn[g]};
                acc = __builtin_amdgcn_mfma_f32_16x16x32_bf16(ch,  rh[g], acc, 0, 0, 0);
                acc = __builtin_amdgcn_mfma_f32_16x16x32_bf16(ch,  rl[g], acc, 0, 0, 0);
                acc = __builtin_amdgcn_mfma_f32_16x16x32_bf16(cl8, rh[g], acc, 0, 0, 0);
                #pragma unroll
                for (int i = 0; i < 4; ++i) {
                    float pm = __uint_as_float((__float_as_uint(acc[i]) & 0xFFFFFF00u)
                                               | (unsigned)((tt << 2) | i));
                    float mx = fmaxf(pm, m1[g][i]);
                    m1[g][i] = fminf(pm, m1[g][i]);
                    m2[g][i] = fminf(m2[g][i], mx);
                }
            }
        }

        int bip[2]; bool flg[2];
        #pragma unroll
        for (int g = 0; g < 2; ++g) {
            // resolve packed (tt<<2)|i -> full code tt*16 + qo*4 + i (order-preserving)
            #pragma unroll
            for (int i = 0; i < 4; ++i) {
                unsigned u = __float_as_uint(m1[g][i]);
                unsigned low = u & 0xFFu;
                unsigned full = ((low & 0xFCu) << 2) | ((unsigned)qo << 2) | (low & 3u);
                m1[g][i] = __uint_as_float((u & 0xFFFFFF00u) | full);
            }
            // merge 4 regs -> (M1, M2)
            float p1 = fminf(m1[g][0], m1[g][1]);
            float ph = fmaxf(m1[g][0], m1[g][1]);
            float p2 = fminf(fminf(m2[g][0], m2[g][1]), ph);
            float s1 = fminf(m1[g][2], m1[g][3]);
            float sh = fmaxf(m1[g][2], m1[g][3]);
            float s2 = fminf(fminf(m2[g][2], m2[g][3]), sh);
            float hh = fmaxf(p1, s1);
            float M1 = fminf(p1, s1);
            float M2 = fminf(fminf(p2, s2), hh);
            // merge across the 4 owner lanes (xor 16, 32) — lands where it's consumed
            #pragma unroll
            for (int off = 16; off <= 32; off <<= 1) {
                float o1 = __shfl_xor(M1, off);
                float o2 = __shfl_xor(M2, off);
                float h2 = fmaxf(M1, o1);
                M1 = fminf(M1, o1);
                M2 = fminf(fminf(M2, o2), h2);
            }
            bip[g] = (int)(__float_as_uint(M1) & 0xFFu);
            float a1 = __uint_as_float(__float_as_uint(M1) & 0xFFFFFF00u);
            float a2 = __uint_as_float(__float_as_uint(M2) & 0xFFFFFF00u);
            // trunc-split bf16x3 error + packing quantization, 4x margin (half-units)
            float eps = fmaf(sqrtf(rn[g]), 1.5e-3f, fmaf(fabsf(a1), 3e-5f, 1e-6f));
            flg[g] = (a2 - a1) < eps;
        }

        // ---- rare: exact fp32 wave-cooperative rescan of ambiguous points ----
        #pragma unroll
        for (int g = 0; g < 2; ++g) {
            unsigned long long bm = __ballot((l < 16) && flg[g]);
            while (bm) {
                int p = __ffsll(bm) - 1;
                bm &= bm - 1;
                float rp[32];
                #pragma unroll
                for (int qq = 0; qq < 4; ++qq)
                    #pragma unroll
                    for (int j = 0; j < 8; ++j)
                        rp[qq*8 + j] = __shfl(r[g][j], qq*16 + p);
                float bests = FLTMAX; int bestk = 0;
                #pragma unroll
                for (int c = 0; c < 4; ++c) {
                    int k = (c << 6) + l;
                    const float4* ck = (const float4*)(cbq + (size_t)k * DIMS);
                    float a0=0.f,a1=0.f,a2=0.f,a3=0.f;
                    #pragma unroll
                    for (int j = 0; j < 8; ++j) {
                        float4 f = ck[j];
                        a0 = fmaf(rp[4*j+0], f.x, a0);
                        a1 = fmaf(rp[4*j+1], f.y, a1);
                        a2 = fmaf(rp[4*j+2], f.z, a2);
                        a3 = fmaf(rp[4*j+3], f.w, a3);
                    }
                    float sc = fmaf(-2.f, (a0+a1)+(a2+a3), 2.f * s_hn[k]);
                    bool lt = sc < bests;
                    bests = lt ? sc : bests;  bestk = lt ? k : bestk;
                }
                #pragma unroll
                for (int off = 1; off < 64; off <<= 1) {
                    float so = __shfl_xor(bests, off);
                    int   ko = __shfl_xor(bestk, off);
                    bool take = (so < bests) || (so == bests && ko < bestk);
                    bests = take ? so : bests;
                    bestk = take ? ko : bestk;
                }
                if (cl == p) bip[g] = bestk;
            }
        }

        // ---- gather chosen codes (exact fp32), update residual, loss, indices ----
        #pragma unroll
        for (int g = 0; g < 2; ++g) {
            const float4* cq = (const float4*)(cbq + (size_t)bip[g] * DIMS + qo * 8);
            float4 c0 = cq[0], c1 = cq[1];
            r[g][0]-=c0.x; r[g][1]-=c0.y; r[g][2]-=c0.z; r[g][3]-=c0.w;
            r[g][4]-=c1.x; r[g][5]-=c1.y; r[g][6]-=c1.z; r[g][7]-=c1.w;
            #pragma unroll
            for (int j = 0; j < 8; ++j) la = fmaf(r[g][j], r[g][j], la);
            if (l < 16)
                out_idx[(size_t)(base + g*16 + l) * NQ + q] = (float)bip[g];
        }
    }

    // ---- epilogue: x_q = x - r_final ----
    #pragma unroll
    for (int g = 0; g < 2; ++g) {
        size_t o = (size_t)(base + g*16 + cl) * DIMS + qo * 8;
        const float4* xp = (const float4*)(x + o);
        float4 a = xp[0], c = xp[1];
        float4* op = (float4*)(out_xq + o);
        op[0] = make_float4(a.x - r[g][0], a.y - r[g][1], a.z - r[g][2], a.w - r[g][3]);
        op[1] = make_float4(c.x - r[g][4], c.y - r[g][5], c.z - r[g][6], c.w - r[g][7]);
    }

    // ---- loss: wave -> block -> one atomicAdd ----
    float v = la;
    #pragma unroll
    for (int off = 1; off < 64; off <<= 1)
        v += __shfl_xor(v, off);
    if (l == 0) s_ws[w] = v;
    __syncthreads();
    if (t == 0) {
        const float scale = (1.0f + BETA) / ((float)NQ * 262144.0f * (float)DIMS);
        atomicAdd(out_loss, (s_ws[0] + s_ws[1] + s_ws[2] + s_ws[3]) * scale);
    }
}

extern "C" void kernel_launch(void* const* d_in, const int* in_sizes, int n_in,
                              void* d_out, int out_size, void* d_ws, size_t ws_size,
                              hipStream_t stream) {
    const float* x  = (const float*)d_in[0];   // [N, 32]
    const float* cb = (const float*)d_in[1];   // [4, 256, 32]
    float* out = (float*)d_out;

    const int N = in_sizes[0] / DIMS;          // 262144
    float* out_xq   = out;
    float* out_loss = out + (size_t)N * DIMS;
    float* out_idx  = out + (size_t)N * DIMS + 1;

    hipMemsetAsync(out_loss, 0, sizeof(float), stream);

    rvq_kernel<<<dim3(N / 128), dim3(256), 0, stream>>>(x, cb, out_xq, out_loss, out_idx);
}

// Round 8
// 243.062 us; speedup vs baseline: 1.6037x; 1.6037x over previous
//
#include <hip/hip_runtime.h>

// Problem constants: N=262144, D=32, Q=4, K=256
#define DIMS 32
#define NQ   4
#define KC   256
#define BETA 0.25f
#define FLTMAX 3.402823466e38f

typedef __attribute__((ext_vector_type(8))) short  short8;   // 8 bf16 (4 VGPRs)
typedef __attribute__((ext_vector_type(4))) float  floatx4;  // MFMA acc

// TRANSPOSED MFMA: A = codes (from LDS, negated, trunc-split bf16), B = residuals.
// D[row = code-in-tile = qo*4+i][col = point = l&15]  (C/D: col=lane&15, row=(lane>>4)*4+reg)
// => each point's scores live in lanes {qo*16+cl} — the same lanes that own its dims:
//    2-round shfl reduction, no broadcast block.
// acc init = 0.5||c||^2 + 0.5||r||^2; codes negated at staging => acc = dist^2/2.
// Code index packed in low 8 mantissa bits as (tt<<2)|i, resolved before merging.
// ROUND-8 NOTE: this is round 6's harness-validated source with ONE change:
// __launch_bounds__(256,2) instead of (256,4). r6's (256,4) forced VGPR=64 ->
// scratch spills (FETCH 277MB/WRITE 363MB, VALUBusy 23%). (256,2) is the
// r5-proven budget (~128 VGPR, clean traffic).
__launch_bounds__(256, 2)
__global__ void rvq_kernel(const float* __restrict__ x,
                           const float* __restrict__ cb,      // [NQ, KC, DIMS]
                           float* __restrict__ out_xq,        // [N, DIMS]
                           float* __restrict__ out_loss,      // [1] pre-zeroed
                           float* __restrict__ out_idx)       // [N, NQ] as float
{
    // entry e = tt*64 + qo*16 + cl  <->  code tt*16+cl, dim-octet qo; 16 B each.
    __shared__ __align__(16) short s_hi[1024 * 8];   // 16 KB
    __shared__ __align__(16) short s_lo[1024 * 8];   // 16 KB
    __shared__ float s_hn[KC];                       // 1 KB: 0.5*||c||^2
    __shared__ float s_ws[4];

    const int t  = threadIdx.x;
    const int l  = t & 63;
    const int w  = t >> 6;
    const int qo = l >> 4;       // dim-octet (0..3)
    const int cl = l & 15;       // point-in-group / code-in-tile

    const int base = blockIdx.x * 128 + w * 32;   // wave covers 32 points (2 groups of 16)

    // ---- residuals: [group][8 dims], 16 VGPRs ----
    float r[2][8];
    #pragma unroll
    for (int g = 0; g < 2; ++g) {
        const float4* xp = (const float4*)(x + (size_t)(base + g*16 + cl) * DIMS + qo * 8);
        float4 a = xp[0], c = xp[1];
        r[g][0]=a.x; r[g][1]=a.y; r[g][2]=a.z; r[g][3]=a.w;
        r[g][4]=c.x; r[g][5]=c.y; r[g][6]=c.z; r[g][7]=c.w;
    }

    float la = 0.f;   // sum over own dims of ||r_new||^2, all stages

    for (int q = 0; q < NQ; ++q) {
        const float* cbq = cb + (size_t)q * KC * DIMS;
        __syncthreads();   // previous stage's LDS consumers done

        // ---- stage: half-norms (exact fp32), thread t <-> code t ----
        {
            const float4* c4 = (const float4*)(cbq + (size_t)t * DIMS);
            float s0=0.f,s1=0.f,s2=0.f,s3=0.f;
            #pragma unroll
            for (int j = 0; j < 8; ++j) {
                float4 f = c4[j];
                s0 = fmaf(f.x,f.x,s0); s1 = fmaf(f.y,f.y,s1);
                s2 = fmaf(f.z,f.z,s2); s3 = fmaf(f.w,f.w,s3);
            }
            s_hn[t] = 0.5f * ((s0+s1)+(s2+s3));
        }
        // ---- stage: negated trunc-split codebook; 1 thread = 1 full 16B entry ----
        // write pattern: lanes -> sequential dwords => conflict-free ds_write_b128
        #pragma unroll
        for (int it = 0; it < 4; ++it) {
            int e = it * 256 + t;
            const float4* src = (const float4*)(cbq + (size_t)((e>>6)*16 + (e&15)) * DIMS
                                                + ((e>>4)&3) * 8);
            float4 f0 = src[0], f1 = src[1];
            unsigned u[8];
            u[0]=__float_as_uint(f0.x)^0x80000000u; u[1]=__float_as_uint(f0.y)^0x80000000u;
            u[2]=__float_as_uint(f0.z)^0x80000000u; u[3]=__float_as_uint(f0.w)^0x80000000u;
            u[4]=__float_as_uint(f1.x)^0x80000000u; u[5]=__float_as_uint(f1.y)^0x80000000u;
            u[6]=__float_as_uint(f1.z)^0x80000000u; u[7]=__float_as_uint(f1.w)^0x80000000u;
            int4 hp, lp;
            int* hpi = (int*)&hp; int* lpi = (int*)&lp;
            #pragma unroll
            for (int p = 0; p < 4; ++p) {
                unsigned a = u[2*p], b = u[2*p+1];
                hpi[p] = (int)((b & 0xFFFF0000u) | (a >> 16));
                float ea = __uint_as_float(a) - __uint_as_float(a & 0xFFFF0000u);
                float eb = __uint_as_float(b) - __uint_as_float(b & 0xFFFF0000u);
                unsigned ua = __float_as_uint(ea), ub = __float_as_uint(eb);
                lpi[p] = (int)((ub & 0xFFFF0000u) | (ua >> 16));
            }
            *(int4*)(&s_hi[e << 3]) = hp;
            *(int4*)(&s_lo[e << 3]) = lp;
        }
        __syncthreads();

        // ---- B-fragments: trunc-split bf16 of residual (unnegated) ----
        short8 rh[2], rl[2];
        #pragma unroll
        for (int g = 0; g < 2; ++g) {
            int4 hp, lp;
            int* hpi = (int*)&hp; int* lpi = (int*)&lp;
            #pragma unroll
            for (int p = 0; p < 4; ++p) {
                unsigned a = __float_as_uint(r[g][2*p]);
                unsigned b = __float_as_uint(r[g][2*p+1]);
                hpi[p] = (int)((b & 0xFFFF0000u) | (a >> 16));
                float ea = r[g][2*p]   - __uint_as_float(a & 0xFFFF0000u);
                float eb = r[g][2*p+1] - __uint_as_float(b & 0xFFFF0000u);
                unsigned ua = __float_as_uint(ea), ub = __float_as_uint(eb);
                lpi[p] = (int)((ub & 0xFFFF0000u) | (ua >> 16));
            }
            rh[g] = *(short8*)&hp;
            rl[g] = *(short8*)&lp;
        }

        // ---- ||r||^2 per point (every lane ends with its point's value) ----
        float rn[2], hrn[2];
        #pragma unroll
        for (int g = 0; g < 2; ++g) {
            float p0 = 0.f;
            #pragma unroll
            for (int j = 0; j < 8; ++j) p0 = fmaf(r[g][j], r[g][j], p0);
            p0 += __shfl_xor(p0, 16);
            p0 += __shfl_xor(p0, 32);
            rn[g] = p0;
            hrn[g] = 0.5f * p0;
        }

        // ---- MFMA tile loop ----
        float m1[2][4], m2[2][4];
        #pragma unroll
        for (int g = 0; g < 2; ++g)
            #pragma unroll
            for (int i = 0; i < 4; ++i) { m1[g][i] = FLTMAX; m2[g][i] = FLTMAX; }

        #pragma unroll 4
        for (int tt = 0; tt < 16; ++tt) {
            const short8 ch  = *(const short8*)(&s_hi[((tt << 6) + l) << 3]);
            const short8 cl8 = *(const short8*)(&s_lo[((tt << 6) + l) << 3]);
            const float4 hn4 = *(const float4*)(&s_hn[(tt << 4) + (qo << 2)]);  // broadcast
            #pragma unroll
            for (int g = 0; g < 2; ++g) {
                floatx4 acc = {hn4.x + hrn[g], hn4.y + hrn[g],
                               hn4.z + hrn[g], hn4.w + hrn[g]};
                acc = __builtin_amdgcn_mfma_f32_16x16x32_bf16(ch,  rh[g], acc, 0, 0, 0);
                acc = __builtin_amdgcn_mfma_f32_16x16x32_bf16(ch,  rl[g], acc, 0, 0, 0);
                acc = __builtin_amdgcn_mfma_f32_16x16x32_bf16(cl8, rh[g], acc, 0, 0, 0);
                #pragma unroll
                for (int i = 0; i < 4; ++i) {
                    float pm = __uint_as_float((__float_as_uint(acc[i]) & 0xFFFFFF00u)
                                               | (unsigned)((tt << 2) | i));
                    float mx = fmaxf(pm, m1[g][i]);
                    m1[g][i] = fminf(pm, m1[g][i]);
                    m2[g][i] = fminf(m2[g][i], mx);
                }
            }
        }

        int bip[2]; bool flg[2];
        #pragma unroll
        for (int g = 0; g < 2; ++g) {
            // resolve packed (tt<<2)|i -> full code tt*16 + qo*4 + i (order-preserving)
            #pragma unroll
            for (int i = 0; i < 4; ++i) {
                unsigned u = __float_as_uint(m1[g][i]);
                unsigned low = u & 0xFFu;
                unsigned full = ((low & 0xFCu) << 2) | ((unsigned)qo << 2) | (low & 3u);
                m1[g][i] = __uint_as_float((u & 0xFFFFFF00u) | full);
            }
            // merge 4 regs -> (M1, M2)
            float p1 = fminf(m1[g][0], m1[g][1]);
            float ph = fmaxf(m1[g][0], m1[g][1]);
            float p2 = fminf(fminf(m2[g][0], m2[g][1]), ph);
            float s1 = fminf(m1[g][2], m1[g][3]);
            float sh = fmaxf(m1[g][2], m1[g][3]);
            float s2 = fminf(fminf(m2[g][2], m2[g][3]), sh);
            float hh = fmaxf(p1, s1);
            float M1 = fminf(p1, s1);
            float M2 = fminf(fminf(p2, s2), hh);
            // merge across the 4 owner lanes (xor 16, 32) — lands where it's consumed
            #pragma unroll
            for (int off = 16; off <= 32; off <<= 1) {
                float o1 = __shfl_xor(M1, off);
                float o2 = __shfl_xor(M2, off);
                float h2 = fmaxf(M1, o1);
                M1 = fminf(M1, o1);
                M2 = fminf(fminf(M2, o2), h2);
            }
            bip[g] = (int)(__float_as_uint(M1) & 0xFFu);
            float a1 = __uint_as_float(__float_as_uint(M1) & 0xFFFFFF00u);
            float a2 = __uint_as_float(__float_as_uint(M2) & 0xFFFFFF00u);
            // trunc-split bf16x3 error + packing quantization, 4x margin (half-units)
            float eps = fmaf(sqrtf(rn[g]), 1.5e-3f, fmaf(fabsf(a1), 3e-5f, 1e-6f));
            flg[g] = (a2 - a1) < eps;
        }

        // ---- rare: exact fp32 wave-cooperative rescan of ambiguous points ----
        #pragma unroll
        for (int g = 0; g < 2; ++g) {
            unsigned long long bm = __ballot((l < 16) && flg[g]);
            while (bm) {
                int p = __ffsll(bm) - 1;
                bm &= bm - 1;
                float rp[32];
                #pragma unroll
                for (int qq = 0; qq < 4; ++qq)
                    #pragma unroll
                    for (int j = 0; j < 8; ++j)
                        rp[qq*8 + j] = __shfl(r[g][j], qq*16 + p);
                float bests = FLTMAX; int bestk = 0;
                #pragma unroll
                for (int c = 0; c < 4; ++c) {
                    int k = (c << 6) + l;
                    const float4* ck = (const float4*)(cbq + (size_t)k * DIMS);
                    float a0=0.f,a1=0.f,a2=0.f,a3=0.f;
                    #pragma unroll
                    for (int j = 0; j < 8; ++j) {
                        float4 f = ck[j];
                        a0 = fmaf(rp[4*j+0], f.x, a0);
                        a1 = fmaf(rp[4*j+1], f.y, a1);
                        a2 = fmaf(rp[4*j+2], f.z, a2);
                        a3 = fmaf(rp[4*j+3], f.w, a3);
                    }
                    float sc = fmaf(-2.f, (a0+a1)+(a2+a3), 2.f * s_hn[k]);
                    bool lt = sc < bests;
                    bests = lt ? sc : bests;  bestk = lt ? k : bestk;
                }
                #pragma unroll
                for (int off = 1; off < 64; off <<= 1) {
                    float so = __shfl_xor(bests, off);
                    int   ko = __shfl_xor(bestk, off);
                    bool take = (so < bests) || (so == bests && ko < bestk);
                    bests = take ? so : bests;
                    bestk = take ? ko : bestk;
                }
                if (cl == p) bip[g] = bestk;
            }
        }

        // ---- gather chosen codes (exact fp32), update residual, loss, indices ----
        #pragma unroll
        for (int g = 0; g < 2; ++g) {
            const float4* cq = (const float4*)(cbq + (size_t)bip[g] * DIMS + qo * 8);
            float4 c0 = cq[0], c1 = cq[1];
            r[g][0]-=c0.x; r[g][1]-=c0.y; r[g][2]-=c0.z; r[g][3]-=c0.w;
            r[g][4]-=c1.x; r[g][5]-=c1.y; r[g][6]-=c1.z; r[g][7]-=c1.w;
            #pragma unroll
            for (int j = 0; j < 8; ++j) la = fmaf(r[g][j], r[g][j], la);
            if (l < 16)
                out_idx[(size_t)(base + g*16 + l) * NQ + q] = (float)bip[g];
        }
    }

    // ---- epilogue: x_q = x - r_final ----
    #pragma unroll
    for (int g = 0; g < 2; ++g) {
        size_t o = (size_t)(base + g*16 + cl) * DIMS + qo * 8;
        const float4* xp = (const float4*)(x + o);
        float4 a = xp[0], c = xp[1];
        float4* op = (float4*)(out_xq + o);
        op[0] = make_float4(a.x - r[g][0], a.y - r[g][1], a.z - r[g][2], a.w - r[g][3]);
        op[1] = make_float4(c.x - r[g][4], c.y - r[g][5], c.z - r[g][6], c.w - r[g][7]);
    }

    // ---- loss: wave -> block -> one atomicAdd ----
    float v = la;
    #pragma unroll
    for (int off = 1; off < 64; off <<= 1)
        v += __shfl_xor(v, off);
    if (l == 0) s_ws[w] = v;
    __syncthreads();
    if (t == 0) {
        const float scale = (1.0f + BETA) / ((float)NQ * 262144.0f * (float)DIMS);
        atomicAdd(out_loss, (s_ws[0] + s_ws[1] + s_ws[2] + s_ws[3]) * scale);
    }
}

extern "C" void kernel_launch(void* const* d_in, const int* in_sizes, int n_in,
                              void* d_out, int out_size, void* d_ws, size_t ws_size,
                              hipStream_t stream) {
    const float* x  = (const float*)d_in[0];   // [N, 32]
    const float* cb = (const float*)d_in[1];   // [4, 256, 32]
    float* out = (float*)d_out;

    const int N = in_sizes[0] / DIMS;          // 262144
    float* out_xq   = out;
    float* out_loss = out + (size_t)N * DIMS;
    float* out_idx  = out + (size_t)N * DIMS + 1;

    hipMemsetAsync(out_loss, 0, sizeof(float), stream);

    rvq_kernel<<<dim3(N / 128), dim3(256), 0, stream>>>(x, cb, out_xq, out_loss, out_idx);
}